// Round 13
// baseline (4042.881 us; speedup 1.0000x reference)
//
#include <hip/hip_runtime.h>
#include <cstdint>

typedef unsigned short u16;
typedef __attribute__((ext_vector_type(4))) float f32x4;
typedef __attribute__((ext_vector_type(8))) short bf16x8;   // 8 bf16 in 4 VGPRs
typedef __attribute__((ext_vector_type(4))) unsigned int u32x4;

constexpr int NB = 1024;   // batch
constexpr int NT = 200;    // time
constexpr int ND = 128;    // input dim
constexpr int NU = 128;    // units
constexpr int NG = 512;    // 4*U gates
constexpr int ROWS = 16;   // batch rows per block
constexpr int NGRP = NB / ROWS;   // 64
constexpr int CST  = 4;    // steps per round
constexpr int RNDS = NT / CST;    // 50
constexpr int IMG_BYTES = CST * ROWS * 512;   // 32768: 4 steps x 16 rows x (2 planes x 128 k) bf16
constexpr int IMG_U16   = IMG_BYTES / 2;

// LDS map (bytes): XIN dbuf [0,64K) | OIMG [64K,96K) | HBUF [96K,112K)
constexpr int LDS_OIMG_B = 65536;
constexpr int LDS_HBUF_B = 98304;
constexpr int LDS_BYTES  = 114688;

__device__ __forceinline__ u16 f2bf(float x) {
    uint32_t u = __builtin_bit_cast(uint32_t, x);
    u = (u + 0x7fffu + ((u >> 16) & 1u)) >> 16;   // RNE
    return (u16)u;
}
__device__ __forceinline__ float bf2f(u16 b) {
    uint32_t u = ((uint32_t)b) << 16;
    return __builtin_bit_cast(float, u);
}
__device__ __forceinline__ float sigm(float x) {
    return __builtin_amdgcn_rcpf(1.f + __expf(-x));
}
__device__ __forceinline__ float tanh_fast(float x) {
    float e = __expf(-2.f * fabsf(x));
    float t = (1.f - e) * __builtin_amdgcn_rcpf(1.f + e);
    return copysignf(t, x);
}

// Canonical chunk-image byte offset: (pos 0..3, row 0..15, plane hi/lo, k 0..127).
// Swizzle keeps ds_read_b128 A-frag reads 2-way (free). Used by the prepass
// writer, the producer's h-image writer, and both readers — consistency by
// construction.
__device__ __forceinline__ uint32_t img_off(int pos, int row, int plane, int k) {
    return (uint32_t)(pos * 8192 + row * 512 +
                      (((plane << 8) + 2 * k) ^ ((row & 15) << 4)));
}

// Poll RELAXED (no L2 inv) + periodic acquire (cross-XCD progress) + one final
// acquire (synchronizes-with + flush stale lines). r8 lesson: acquire every
// poll = L2 inv storm. r11 lesson: release publish = wbl2 storm -> publishes
// are RELAXED after a barrier whose vmcnt(0) drained coherent stores (r12).
__device__ __forceinline__ void spin_gate(const int* p, int need) {
    int k = 0;
    while (__hip_atomic_load(p, __ATOMIC_RELAXED, __HIP_MEMORY_SCOPE_AGENT) < need) {
        __builtin_amdgcn_s_sleep(16);
        if ((++k & 63) == 0)
            (void)__hip_atomic_load(p, __ATOMIC_ACQUIRE, __HIP_MEMORY_SCOPE_AGENT);
    }
    (void)__hip_atomic_load(p, __ATOMIC_ACQUIRE, __HIP_MEMORY_SCOPE_AGENT);
}

// ---- prepass: x fp32 -> split (hi/lo bf16) swizzled chunk images ------------
__global__ void prepass(const float* __restrict__ x, u16* __restrict__ xs) {
    int id = blockIdx.x * blockDim.x + threadIdx.x;
    if (id >= NGRP * RNDS * CST * 16 * 16) return;
    const int blk = id & 15; id >>= 4;
    const int row = id & 15; id >>= 4;
    const int pos = id & 3;  id >>= 2;
    const int fc  = id % RNDS;
    const int grp = id / RNDS;
    const int k0 = blk * 8;
    const int b = grp * ROWS + row, t = fc * CST + pos;
    const float* xp = x + ((size_t)b * NT + t) * ND + k0;
    bf16x8 hi, lo;
    #pragma unroll
    for (int e = 0; e < 8; ++e) {
        const float v = xp[e];
        const u16 h = f2bf(v);
        hi[e] = (short)h;
        lo[e] = (short)f2bf(v - bf2f(h));
    }
    u16* base = xs + (size_t)(grp * RNDS + fc) * IMG_U16;
    *(bf16x8*)(base + (img_off(pos, row, 0, k0) >> 1)) = hi;
    *(bf16x8*)(base + (img_off(pos, row, 1, k0) >> 1)) = lo;
}

// ---- one LSTM layer, 16 rows, 50 rounds x 4 steps ---------------------------
// All global I/O at round boundaries; steps 1-3 have no outstanding vmem so
// their barrier drains are free (the r2-r12 per-step drain stall, removed).
// Weights: 3 register arrays (r6/r10: a 4th forces global remat).
template<bool PROD>
__device__ __forceinline__ void run_layer(
    const float* __restrict__ Wk, const float* __restrict__ Wr,
    const float* __restrict__ Bv,
    const u16* __restrict__ img_in,    // this chain's input images (fc-indexed)
    u16* __restrict__ img_out,         // PROD: h0 image chain base
    float* __restrict__ dout,          // CONS: final output (atomicAdd 0.5*h1)
    int* prog_c, u16* smem, const int dir, const int base_b,
    const int tid, const int q, const int cl, const int uu)
{
    u16* XIN  = smem;                        // 2 x 32KB images
    u16* OIMG = smem + (LDS_OIMG_B >> 1);    // 32KB out-chunk
    u16* HBUF = smem + (LDS_HBUF_B >> 1);    // 16KB h dbuf
    float* OF = (float*)OIMG;                // CONS view: [pos][row][128] f32

    // ---- resident weight fragments
    bf16x8 wkh[4][4], wrh[4][4], wrl[4][4];
    #pragma unroll
    for (int g = 0; g < 4; ++g) {
        const int col = g * NU + uu;
        #pragma unroll
        for (int s = 0; s < 4; ++s) {
            bf16x8 fa, fh, fl;
            #pragma unroll
            for (int j = 0; j < 8; ++j) {
                const int k = s * 32 + q * 8 + j;
                fa[j] = (short)f2bf(Wk[k * NG + col]);
                const float w = Wr[k * NG + col];
                const u16 hi = f2bf(w);
                fh[j] = (short)hi;
                fl[j] = (short)f2bf(w - bf2f(hi));
            }
            wkh[g][s] = fa; wrh[g][s] = fh; wrl[g][s] = fl;
        }
    }
    float bias[4];
    #pragma unroll
    for (int g = 0; g < 4; ++g) bias[g] = Bv[g * NU + uu];

    for (int i = tid; i < 8192; i += 512) HBUF[i] = 0;   // h planes start 0

    // prologue: image 0 -> XIN[0]
    if (!PROD) { if (tid == 0) spin_gate(prog_c, 1); }
    __syncthreads();   // gate broadcast; HBUF zero ordered before use
    {
        const int fc0 = dir ? RNDS - 1 : 0;
        const char* g = (const char*)(img_in + (size_t)fc0 * IMG_U16) + tid * 64;
        char* d = (char*)XIN + tid * 64;
        u32x4 a0 = *(const u32x4*)(g);
        u32x4 a1 = *(const u32x4*)(g + 16);
        u32x4 a2 = *(const u32x4*)(g + 32);
        u32x4 a3 = *(const u32x4*)(g + 48);
        *(u32x4*)(d)      = a0;
        *(u32x4*)(d + 16) = a1;
        *(u32x4*)(d + 32) = a2;
        *(u32x4*)(d + 48) = a3;
    }
    f32x4 cc = {0.f, 0.f, 0.f, 0.f};
    int hp = 0;
    __syncthreads();   // XIN[0] visible

    for (int i = 0; i < RNDS; ++i) {
        const int p  = i & 1;
        const int fc = dir ? (RNDS - 1 - i) : i;

        // ---- A: dump the previous round's out-chunk
        if (i > 0) {
            const int fcp = dir ? (RNDS - i) : (i - 1);
            if (PROD) {
                const uint64_t* ls = (const uint64_t*)((const char*)OIMG + tid * 64);
                uint64_t* gd = (uint64_t*)((char*)(img_out + (size_t)fcp * IMG_U16) + tid * 64);
                #pragma unroll
                for (int e = 0; e < 8; ++e)
                    __hip_atomic_store(&gd[e], ls[e], __ATOMIC_RELAXED,
                                       __HIP_MEMORY_SCOPE_AGENT);
            } else {
                const float* ls = (const float*)((const char*)OIMG + tid * 64);
                const int idx0 = tid * 16;
                const int pos = idx0 >> 11, rem = idx0 & 2047;
                const int r = rem >> 7, u0 = rem & 127;
                const int t = fcp * CST + pos;
                float* gd = dout + ((size_t)(base_b + r) * NT + t) * NU + u0;
                #pragma unroll
                for (int e = 0; e < 16; ++e) atomicAdd(&gd[e], ls[e]);
            }
        }
        // ---- B: consumer gate for the image loaded this round (at j==2)
        if (!PROD && i + 1 < RNDS && tid == 0) spin_gate(prog_c, i + 2);
        __syncthreads();   // gate broadcast; dump reads done before OIMG rewrite
        if (PROD && i > 0 && tid == 0)   // dump stores drained by the barrier
            __hip_atomic_store(prog_c, i, __ATOMIC_RELAXED, __HIP_MEMORY_SCOPE_AGENT);

        // ---- C: 4 steps
        #pragma unroll
        for (int j = 0; j < CST; ++j) {
            const int pos = dir ? (CST - 1 - j) : j;
            const u16* Xp = XIN + p * IMG_U16;

            f32x4 accx[4], acch[4];
            #pragma unroll
            for (int g = 0; g < 4; ++g) {
                accx[g] = (f32x4){bias[g], bias[g], bias[g], bias[g]};
                acch[g] = (f32x4){0.f, 0.f, 0.f, 0.f};
            }
            #pragma unroll
            for (int s = 0; s < 4; ++s) {
                const int k0 = s * 32 + q * 8;
                const uint32_t sw = (uint32_t)((cl & 15) << 4);
                const bf16x8 axh = *(const bf16x8*)(Xp   + ((uint32_t)(pos * 8192 + cl * 512 + ((2 * k0) ^ sw)) >> 1));
                const bf16x8 axl = *(const bf16x8*)(Xp   + ((uint32_t)(pos * 8192 + cl * 512 + ((256 + 2 * k0) ^ sw)) >> 1));
                const bf16x8 ahh = *(const bf16x8*)(HBUF + ((uint32_t)(hp * 8192 + cl * 512 + ((2 * k0) ^ sw)) >> 1));
                const bf16x8 ahl = *(const bf16x8*)(HBUF + ((uint32_t)(hp * 8192 + cl * 512 + ((256 + 2 * k0) ^ sw)) >> 1));
                #pragma unroll
                for (int g = 0; g < 4; ++g) {
                    accx[g] = __builtin_amdgcn_mfma_f32_16x16x32_bf16(axh, wkh[g][s], accx[g], 0, 0, 0);
                    accx[g] = __builtin_amdgcn_mfma_f32_16x16x32_bf16(axl, wkh[g][s], accx[g], 0, 0, 0);
                    acch[g] = __builtin_amdgcn_mfma_f32_16x16x32_bf16(ahh, wrh[g][s], acch[g], 0, 0, 0);
                    acch[g] = __builtin_amdgcn_mfma_f32_16x16x32_bf16(ahl, wrh[g][s], acch[g], 0, 0, 0);
                    acch[g] = __builtin_amdgcn_mfma_f32_16x16x32_bf16(ahh, wrl[g][s], acch[g], 0, 0, 0);
                }
            }

            // stage next image: global -> regs -> LDS, once per round (j==2).
            // XIN[p^1] was last read in round i-1, so writing it here is safe.
            if (j == 2 && i + 1 < RNDS) {
                const int fcn = dir ? (RNDS - 2 - i) : (i + 1);
                const char* g = (const char*)(img_in + (size_t)fcn * IMG_U16) + tid * 64;
                char* d = (char*)XIN + (p ^ 1) * IMG_BYTES + tid * 64;
                u32x4 a0 = *(const u32x4*)(g);
                u32x4 a1 = *(const u32x4*)(g + 16);
                u32x4 a2 = *(const u32x4*)(g + 32);
                u32x4 a3 = *(const u32x4*)(g + 48);
                *(u32x4*)(d)      = a0;
                *(u32x4*)(d + 16) = a1;
                *(u32x4*)(d + 32) = a2;
                *(u32x4*)(d + 48) = a3;
            }

            // gates + state; C/D: col = lane&15 (unit), row = q*4+j (batch row)
            #pragma unroll
            for (int jj = 0; jj < 4; ++jj) {
                const int r = q * 4 + jj;
                const float gi = sigm(accx[0][jj] + acch[0][jj]);
                const float gf = sigm(accx[1][jj] + acch[1][jj]);
                const float gg = tanh_fast(accx[2][jj] + acch[2][jj]);
                const float go = sigm(accx[3][jj] + acch[3][jj]);
                const float cn = gf * cc[jj] + gi * gg;
                cc[jj] = cn;
                const float h = go * tanh_fast(cn);
                const u16 hh = f2bf(h);
                const u16 hl = f2bf(h - bf2f(hh));
                const uint32_t sw = (uint32_t)((r & 15) << 4);
                HBUF[(uint32_t)((hp ^ 1) * 8192 + r * 512 + ((2 * uu) ^ sw)) >> 1]       = hh;
                HBUF[(uint32_t)((hp ^ 1) * 8192 + r * 512 + ((256 + 2 * uu) ^ sw)) >> 1] = hl;
                if (PROD) {
                    OIMG[img_off(pos, r, 0, uu) >> 1] = hh;
                    OIMG[img_off(pos, r, 1, uu) >> 1] = hl;
                } else {
                    OF[(pos * 16 + r) * 128 + uu] = 0.5f * h;
                }
            }
            __syncthreads();   // h/x-image writes visible; j>=1: no vmem outstanding
            hp ^= 1;
        }
    }

    // epilogue: dump the final round's out-chunk
    {
        const int fcp = dir ? 0 : RNDS - 1;
        if (PROD) {
            const uint64_t* ls = (const uint64_t*)((const char*)OIMG + tid * 64);
            uint64_t* gd = (uint64_t*)((char*)(img_out + (size_t)fcp * IMG_U16) + tid * 64);
            #pragma unroll
            for (int e = 0; e < 8; ++e)
                __hip_atomic_store(&gd[e], ls[e], __ATOMIC_RELAXED,
                                   __HIP_MEMORY_SCOPE_AGENT);
            __syncthreads();   // drain all waves' stores
            if (tid == 0)
                __hip_atomic_store(prog_c, RNDS, __ATOMIC_RELAXED,
                                   __HIP_MEMORY_SCOPE_AGENT);
        } else {
            const float* ls = (const float*)((const char*)OIMG + tid * 64);
            const int idx0 = tid * 16;
            const int pos = idx0 >> 11, rem = idx0 & 2047;
            const int r = rem >> 7, u0 = rem & 127;
            const int t = fcp * CST + pos;
            float* gd = dout + ((size_t)(base_b + r) * NT + t) * NU + u0;
            #pragma unroll
            for (int e = 0; e < 16; ++e) atomicAdd(&gd[e], ls[e]);
        }
    }
}

// grid = (64 groups, 2 dirs, 2 layers) = 256 blocks, 112KB LDS -> 1 block/CU,
// all co-resident (producers never wait on consumers -> no deadlock).
__global__ __launch_bounds__(512, 2)
void lstm_scan(const float* __restrict__ fwk, const float* __restrict__ fwrk,
               const float* __restrict__ fwb,
               const float* __restrict__ bwk, const float* __restrict__ bwrk,
               const float* __restrict__ bwb,
               const u16* __restrict__ xs, u16* __restrict__ h0img,
               float* __restrict__ dout, int* __restrict__ prog) {
    extern __shared__ __align__(16) u16 smem[];

    const int tid   = threadIdx.x;
    const int lane  = tid & 63;
    const int wv    = tid >> 6;
    const int grp   = blockIdx.x;       // 0..63
    const int dir   = blockIdx.y;       // 0 fw, 1 bw
    const int layer = blockIdx.z;       // 0 producer, 1 consumer
    const int base_b = grp * ROWS;

    const float* kp = dir ? bwk  : fwk;
    const float* rp = dir ? bwrk : fwrk;
    const float* bp = dir ? bwb  : fwb;
    int* prog_c = prog + dir * NGRP + grp;

    const int q  = lane >> 4;
    const int cl = lane & 15;
    const int uu = (wv << 4) + cl;

    const u16* xchain = xs + (size_t)(grp * RNDS) * IMG_U16;   // dir-agnostic
    u16* hchain = h0img + (size_t)((dir * NGRP + grp) * RNDS) * IMG_U16;

    if (layer == 0) {
        run_layer<true>(kp, rp, bp, xchain, hchain, nullptr, prog_c, smem,
                        dir, base_b, tid, q, cl, uu);
    } else {
        run_layer<false>(kp + ND * NG, rp + NU * NG, bp + NG,
                         hchain, nullptr, dout, prog_c, smem,
                         dir, base_b, tid, q, cl, uu);
    }
}

extern "C" void kernel_launch(void* const* d_in, const int* in_sizes, int n_in,
                              void* d_out, int out_size, void* d_ws, size_t ws_size,
                              hipStream_t stream) {
    const float* x    = (const float*)d_in[0];
    const float* fwk  = (const float*)d_in[1];
    const float* fwrk = (const float*)d_in[2];
    const float* fwb  = (const float*)d_in[3];
    const float* bwk  = (const float*)d_in[4];
    const float* bwrk = (const float*)d_in[5];
    const float* bwb  = (const float*)d_in[6];
    float* out = (float*)d_out;

    // ws: xs images (100MB) | h0 images (200MB) | prog counters
    u16* xs    = (u16*)d_ws;                               // 64*50*32KB
    u16* h0img = xs + (size_t)NGRP * RNDS * IMG_U16;       // 2*64*50*32KB
    int* prog  = (int*)(h0img + (size_t)2 * NGRP * RNDS * IMG_U16);

    hipMemsetAsync(prog, 0, 2 * NGRP * sizeof(int), stream);
    hipMemsetAsync(out, 0, (size_t)out_size * sizeof(float), stream);

    const int pp_total = NGRP * RNDS * CST * 16 * 16;      // 3,276,800
    prepass<<<(pp_total + 255) / 256, 256, 0, stream>>>(x, xs);

    (void)hipFuncSetAttribute((const void*)lstm_scan,
                              hipFuncAttributeMaxDynamicSharedMemorySize,
                              LDS_BYTES);
    lstm_scan<<<dim3(NGRP, 2, 2), 512, LDS_BYTES, stream>>>(
        fwk, fwrk, fwb, bwk, bwrk, bwb, xs, h0img, out, prog);
}

// Round 14
// 1074.820 us; speedup vs baseline: 3.7615x; 3.7615x over previous
//
#include <hip/hip_runtime.h>
#include <cstdint>

typedef unsigned short u16;
typedef __attribute__((ext_vector_type(4))) float f32x4;
typedef __attribute__((ext_vector_type(8))) short bf16x8;   // 8 bf16 in 4 VGPRs
typedef __attribute__((ext_vector_type(4))) u16 u16x4;

constexpr int NB = 1024;   // batch
constexpr int NT = 200;    // time
constexpr int ND = 128;    // input dim
constexpr int NU = 128;    // units
constexpr int NG = 512;    // 4*U gates
constexpr int ROWS = 16;   // batch rows per block (MFMA M)
constexpr int NGRP = NB / ROWS;           // 64 groups
constexpr int CHUNK = 8;   // consumer gate granularity (divides NT)
constexpr int ABUF = ROWS * 512;          // 8192 u16 per A buffer
constexpr int LDS_A_ELEMS = 2 * ABUF;     // double-buffered: 32 KiB

__device__ __forceinline__ u16 f2bf(float x) {
    uint32_t u = __builtin_bit_cast(uint32_t, x);
    u = (u + 0x7fffu + ((u >> 16) & 1u)) >> 16;   // RNE
    return (u16)u;
}
__device__ __forceinline__ float bf2f(u16 b) {
    uint32_t u = ((uint32_t)b) << 16;
    return __builtin_bit_cast(float, u);
}
__device__ __forceinline__ float sigm(float x) {
    return __builtin_amdgcn_rcpf(1.f + __expf(-x));
}
__device__ __forceinline__ float tanh_fast(float x) {
    float e = __expf(-2.f * fabsf(x));
    float t = (1.f - e) * __builtin_amdgcn_rcpf(1.f + e);
    return copysignf(t, x);
}

// Poll RELAXED (no L2 inv) + periodic acquire (cross-XCD progress) + one final
// acquire (synchronizes-with edge). r8: acquire every poll = L2 inv storm.
// r11: release publish = wbl2 storm. r12: coherent stores + relaxed publish.
__device__ __forceinline__ void spin_gate(const int* p, int need) {
    int k = 0;
    while (__hip_atomic_load(p, __ATOMIC_RELAXED, __HIP_MEMORY_SCOPE_AGENT) < need) {
        __builtin_amdgcn_s_sleep(16);
        if ((++k & 63) == 0)
            (void)__hip_atomic_load(p, __ATOMIC_ACQUIRE, __HIP_MEMORY_SCOPE_AGENT);
    }
    (void)__hip_atomic_load(p, __ATOMIC_ACQUIRE, __HIP_MEMORY_SCOPE_AGENT);
}

// One LSTM layer scan for 16 batch rows. 3 register weight arrays — exactly 3
// fit under the 256-reg/wave cap at 2 waves/SIMD (r6/r10/r13: anything more
// forces global remat, FETCH 7-17GB). No Wk_lo (r10: absmax 0.0112 < 0.0188).
// Double-buffered A -> ONE __syncthreads/step.
// r14: h stores are DELAYED ONE STEP (kept in 4 regs, issued at the top of the
// next step) so the per-step barrier's vmcnt(0) never waits on a young
// coherent store; publish needs no waitcnt (the barrier proved all waves'
// older stores drained). r12's defensive vmcnt in the publish path made tid0
// stall on its own fresh prefetch every step — removed.
template<bool PROD, bool CONS>
__device__ __forceinline__ void run_layer(
    const float* __restrict__ Wk, const float* __restrict__ Wr,
    const float* __restrict__ Bv,
    const float* __restrict__ src, float* __restrict__ dst,
    u16* A, int* prog_c,
    const int dir, const int base_b,
    const int tid, const int q, const int cl, const int uu,
    const int sr, const int sc)
{
    // ---- resident weight fragments (B-side)
    bf16x8 wkh[4][4], wrh[4][4], wrl[4][4];
    #pragma unroll
    for (int g = 0; g < 4; ++g) {
        const int col = g * NU + uu;
        #pragma unroll
        for (int s = 0; s < 4; ++s) {
            bf16x8 fa, fh, fl;
            #pragma unroll
            for (int j = 0; j < 8; ++j) {
                const int k = s * 32 + q * 8 + j;
                fa[j] = (short)f2bf(Wk[k * NG + col]);
                const float w = Wr[k * NG + col];
                const u16 hi = f2bf(w);
                fh[j] = (short)hi;
                fl[j] = (short)f2bf(w - bf2f(hi));
            }
            wkh[g][s] = fa; wrh[g][s] = fh; wrl[g][s] = fl;
        }
    }
    float bias[4];
    #pragma unroll
    for (int g = 0; g < 4; ++g) bias[g] = Bv[g * NU + uu];

    for (int i = tid; i < LDS_A_ELEMS; i += 512) A[i] = 0;   // h planes start 0
    f32x4 cc = {0.f, 0.f, 0.f, 0.f};
    float hv[4];      // h_{t-1} carried in regs; stored one step late
    int tprev = -1;   // time index of the carried h

    const size_t srow = (size_t)(base_b + sr) * (NT * NU) + sc;
    const uint32_t stg = (uint32_t)(sr * 1024 + ((2 * sc) ^ ((sr & 15) << 4))) >> 1;

    // consumer pre-gate: chunk 0 (no in-loop gate) reads through x_{t(9)};
    // publish semantics: p = data through index p-1 -> need CHUNK+3 = 11
    if (CONS && tid == 0) spin_gate(prog_c, (CHUNK + 3 < NT) ? CHUNK + 3 : NT);
    __syncthreads();   // zeroing ordered before staging (r4 lesson) + gate broadcast

    // prologue: stage x0 into buffer 0; prefetch x1
    {
        const float4 v = *(const float4*)&src[srow + (size_t)(dir ? NT - 1 : 0) * NU];
        const float vv[4] = {v.x, v.y, v.z, v.w};
        u16x4 hi4, lo4;
        #pragma unroll
        for (int e = 0; e < 4; ++e) {
            const u16 h = f2bf(vv[e]);
            hi4[e] = h;
            lo4[e] = f2bf(vv[e] - bf2f(h));
        }
        *(u16x4*)&A[stg]       = hi4;
        *(u16x4*)&A[stg + 128] = lo4;
    }
    float4 cur = *(const float4*)&src[srow + (size_t)(dir ? NT - 2 : 1) * NU];
    __syncthreads();   // x0 staged, visible

    int p = 0;
    for (int cs = 0; cs < NT; cs += CHUNK) {
        // gate chunk cs: prefetches through x_{t(cs+9)} -> need p >= cs+11
        if (CONS && cs > 0) {
            if (tid == 0) {
                const int need = (cs + CHUNK + 3 < NT) ? cs + CHUNK + 3 : NT;
                spin_gate(prog_c, need);
            }
            __syncthreads();
        }

        for (int step = cs; step < cs + CHUNK; ++step) {
            const int t = dir ? (NT - 1 - step) : step;
            const u16* Ard = A + p * ABUF;
            u16*       Awr = A + (p ^ 1) * ABUF;

            // ---- store h_{t_prev} (computed LAST step): a full step old by
            // the next barrier -> the drain there is free
            if (tprev >= 0) {
                #pragma unroll
                for (int j = 0; j < 4; ++j) {
                    const int r = q * 4 + j;
                    __hip_atomic_store(
                        &dst[(size_t)(base_b + r) * (NT * NU) + (size_t)tprev * NU + uu],
                        hv[j], __ATOMIC_RELAXED, __HIP_MEMORY_SCOPE_AGENT);
                }
            }

            // ---- stage x_{t+1} (prefetched last step) into the NEXT buffer
            if (step + 1 < NT) {
                const float vv[4] = {cur.x, cur.y, cur.z, cur.w};
                u16x4 hi4, lo4;
                #pragma unroll
                for (int e = 0; e < 4; ++e) {
                    const u16 h = f2bf(vv[e]);
                    hi4[e] = h;
                    lo4[e] = f2bf(vv[e] - bf2f(h));
                }
                *(u16x4*)&Awr[stg]       = hi4;   // x_hi: k in [0,128)
                *(u16x4*)&Awr[stg + 128] = lo4;   // x_lo: k in [128,256)
            }
            // ---- prefetch x_{t+2} for next step's staging
            if (step + 2 < NT) {
                const int tf = dir ? (NT - 3 - step) : (step + 2);
                cur = *(const float4*)&src[srow + (size_t)tf * NU];
            }

            f32x4 accx[4], acch[4];   // x-side (carries bias) and h-side chains
            #pragma unroll
            for (int g = 0; g < 4; ++g) {
                accx[g] = (f32x4){bias[g], bias[g], bias[g], bias[g]};
                acch[g] = (f32x4){0.f, 0.f, 0.f, 0.f};
            }

            #pragma unroll
            for (int s = 0; s < 4; ++s) {
                const uint32_t ab =
                    (uint32_t)(cl * 1024 + ((s * 64 + q * 16) ^ ((cl & 15) << 4)));
                const bf16x8 axh = *(const bf16x8*)&Ard[(ab >> 1)];
                const bf16x8 axl = *(const bf16x8*)&Ard[(ab >> 1) + 128];
                const bf16x8 ahh = *(const bf16x8*)&Ard[(ab >> 1) + 256];
                const bf16x8 ahl = *(const bf16x8*)&Ard[(ab >> 1) + 384];
                #pragma unroll
                for (int g = 0; g < 4; ++g) {
                    accx[g] = __builtin_amdgcn_mfma_f32_16x16x32_bf16(axh, wkh[g][s], accx[g], 0, 0, 0);
                    accx[g] = __builtin_amdgcn_mfma_f32_16x16x32_bf16(axl, wkh[g][s], accx[g], 0, 0, 0);
                    acch[g] = __builtin_amdgcn_mfma_f32_16x16x32_bf16(ahh, wrh[g][s], acch[g], 0, 0, 0);
                    acch[g] = __builtin_amdgcn_mfma_f32_16x16x32_bf16(ahl, wrh[g][s], acch[g], 0, 0, 0);
                    acch[g] = __builtin_amdgcn_mfma_f32_16x16x32_bf16(ahh, wrl[g][s], acch[g], 0, 0, 0);
                }
            }

            // gates + state; C/D: col = lane&15 (unit), row = q*4+j (batch row)
            #pragma unroll
            for (int j = 0; j < 4; ++j) {
                const int r = q * 4 + j;
                const float gi = sigm(accx[0][j] + acch[0][j]);
                const float gf = sigm(accx[1][j] + acch[1][j]);
                const float gg = tanh_fast(accx[2][j] + acch[2][j]);
                const float go = sigm(accx[3][j] + acch[3][j]);
                const float cn = gf * cc[j] + gi * gg;
                cc[j] = cn;
                const float h = go * tanh_fast(cn);
                hv[j] = h;                        // delayed global store
                const u16 hh = f2bf(h);
                const u16 hl = f2bf(h - bf2f(hh));
                const uint32_t hb = (uint32_t)(r * 1024 + ((2 * uu) ^ ((r & 15) << 4)));
                Awr[(hb >> 1) + 256] = hh;   // h_hi plane of the NEXT buffer
                Awr[(hb >> 1) + 384] = hl;   // h_lo plane
            }
            tprev = t;

            __syncthreads();   // the ONLY per-step barrier: p-reads done,
                               // p^1 writes visible; vmcnt drain is ~free
                               // (youngest global op is one step old)
            // publish p=step: h0[0..step-1] stored AND drained (each wave's
            // h_{step-1} store was issued at this step's top, drained by the
            // barrier). No waitcnt needed — the barrier is the proof.
            if (PROD && tid == 0 && step)
                __hip_atomic_store(prog_c, step, __ATOMIC_RELAXED,
                                   __HIP_MEMORY_SCOPE_AGENT);
            p ^= 1;
        }
    }

    // epilogue: store the final h (t = tprev), drain, publish completion
    #pragma unroll
    for (int j = 0; j < 4; ++j) {
        const int r = q * 4 + j;
        __hip_atomic_store(
            &dst[(size_t)(base_b + r) * (NT * NU) + (size_t)tprev * NU + uu],
            hv[j], __ATOMIC_RELAXED, __HIP_MEMORY_SCOPE_AGENT);
    }
    __syncthreads();   // all waves' final stores drained (vmcnt(0) at barrier)
    if (PROD && tid == 0)
        __hip_atomic_store(prog_c, NT, __ATOMIC_RELAXED, __HIP_MEMORY_SCOPE_AGENT);
}

// grid = (64 groups, 2 dirs, 2 layers) = 256 blocks = 1 per CU, all
// co-resident -> consumer spins cannot deadlock (producers never wait).
__global__ __launch_bounds__(512, 2)
void lstm_scan(const float* __restrict__ x,
               const float* __restrict__ fwk, const float* __restrict__ fwrk,
               const float* __restrict__ fwb,
               const float* __restrict__ bwk, const float* __restrict__ bwrk,
               const float* __restrict__ bwb,
               float* __restrict__ buf_fw, float* __restrict__ buf_bw,
               int* __restrict__ prog) {
    __shared__ __align__(16) u16 A[LDS_A_ELEMS];   // 2 x [16][512] bf16, swizzled

    const int tid   = threadIdx.x;
    const int lane  = tid & 63;
    const int wv    = tid >> 6;         // wave 0..7
    const int grp   = blockIdx.x;       // 0..63
    const int dir   = blockIdx.y;       // 0 = fw, 1 = bw
    const int layer = blockIdx.z;       // 0 = producer, 1 = consumer
    const int base_b = grp * ROWS;

    const float* kp = dir ? bwk  : fwk;
    const float* rp = dir ? bwrk : fwrk;
    const float* bp = dir ? bwb  : fwb;
    float* buf = dir ? buf_bw : buf_fw;
    int* prog_c = prog + dir * NGRP + grp;

    const int q  = lane >> 4;           // k-group 0..3
    const int cl = lane & 15;           // A-row / B-col within tile
    const int uu = (wv << 4) + cl;      // unit 0..127 owned by this lane

    const int sr = tid >> 5;            // staging row 0..15
    const int sc = (tid & 31) << 2;     // staging col 0..124

    if (layer == 0) {
        // layer 0: x -> buf (h0), publishing progress per step
        run_layer<true, false>(kp, rp, bp, x, buf, A, prog_c,
                               dir, base_b, tid, q, cl, uu, sr, sc);
    } else {
        // layer 1: buf (h0) -> buf in-place (h1), gated on producer progress.
        // In-place safe: h1[t] is stored ~3 steps after h0[t]'s last read.
        run_layer<false, true>(kp + ND * NG, rp + NU * NG, bp + NG,
                               buf, buf, A, prog_c,
                               dir, base_b, tid, q, cl, uu, sr, sc);
    }
}

// ---- merge: out = 0.5*(fw + bw) ---------------------------------------------
__global__ void merge_out(const float* __restrict__ a, const float* __restrict__ b,
                          float* __restrict__ o, int nvec) {
    int i = blockIdx.x * blockDim.x + threadIdx.x;
    const int st = gridDim.x * blockDim.x;
    for (; i < nvec; i += st) {
        const float4 va = ((const float4*)a)[i];
        const float4 vb = ((const float4*)b)[i];
        float4 r;
        r.x = 0.5f * (va.x + vb.x);
        r.y = 0.5f * (va.y + vb.y);
        r.z = 0.5f * (va.z + vb.z);
        r.w = 0.5f * (va.w + vb.w);
        ((float4*)o)[i] = r;
    }
}

extern "C" void kernel_launch(void* const* d_in, const int* in_sizes, int n_in,
                              void* d_out, int out_size, void* d_ws, size_t ws_size,
                              hipStream_t stream) {
    const float* x    = (const float*)d_in[0];
    const float* fwk  = (const float*)d_in[1];
    const float* fwrk = (const float*)d_in[2];
    const float* fwb  = (const float*)d_in[3];
    const float* bwk  = (const float*)d_in[4];
    const float* bwrk = (const float*)d_in[5];
    const float* bwb  = (const float*)d_in[6];
    float* out = (float*)d_out;

    const size_t seq = (size_t)NB * NT * NU;     // 26,214,400 elements
    float* buf_fw = (float*)d_ws;                // fw chain h (h0 then h1 in-place)
    float* buf_bw = buf_fw + seq;                // bw chain h
    int*   prog   = (int*)(buf_bw + seq);        // per-chain progress counters

    // progress counters must be zero at every launch (deterministic replay)
    hipMemsetAsync(prog, 0, 2 * NGRP * sizeof(int), stream);

    lstm_scan<<<dim3(NGRP, 2, 2), 512, 0, stream>>>(
        x, fwk, fwrk, fwb, bwk, bwrk, bwb, buf_fw, buf_bw, prog);

    const int nvec = (int)(seq / 4);
    merge_out<<<2048, 256, 0, stream>>>(buf_fw, buf_bw, out, nvec);
}

// Round 15
// 982.135 us; speedup vs baseline: 4.1164x; 1.0944x over previous
//
#include <hip/hip_runtime.h>
#include <cstdint>

typedef unsigned short u16;
typedef __attribute__((ext_vector_type(4))) float f32x4;
typedef __attribute__((ext_vector_type(8))) short bf16x8;   // 8 bf16 in 4 VGPRs
typedef __attribute__((ext_vector_type(4))) u16 u16x4;

constexpr int NB = 1024;   // batch
constexpr int NT = 200;    // time
constexpr int ND = 128;    // input dim
constexpr int NU = 128;    // units
constexpr int NG = 512;    // 4*U gates
constexpr int ROWS = 16;   // batch rows per block (MFMA M)
constexpr int NGRP = NB / ROWS;           // 64 groups
constexpr int CHUNK = 8;   // consumer gate granularity (divides NT)
constexpr int ABUF = ROWS * 512;          // 8192 u16 per A buffer
constexpr int LDS_A_ELEMS = 2 * ABUF;     // double-buffered: 32 KiB

__device__ __forceinline__ u16 f2bf(float x) {
    uint32_t u = __builtin_bit_cast(uint32_t, x);
    u = (u + 0x7fffu + ((u >> 16) & 1u)) >> 16;   // RNE
    return (u16)u;
}
__device__ __forceinline__ float bf2f(u16 b) {
    uint32_t u = ((uint32_t)b) << 16;
    return __builtin_bit_cast(float, u);
}
__device__ __forceinline__ float sigm(float x) {
    return __builtin_amdgcn_rcpf(1.f + __expf(-x));
}
__device__ __forceinline__ float tanh_fast(float x) {
    float e = __expf(-2.f * fabsf(x));
    float t = (1.f - e) * __builtin_amdgcn_rcpf(1.f + e);
    return copysignf(t, x);
}

// Poll RELAXED (no L2 inv) + periodic acquire (cross-XCD progress guarantee)
// + one final acquire (synchronizes-with edge). r8: acquire every poll = L2
// inv storm. r11: release publish = wbl2 storm. r12: coherent stores +
// relaxed publish, ordering proven by the barrier's per-wave vmcnt drain.
__device__ __forceinline__ void spin_gate(const int* p, int need) {
    int k = 0;
    while (__hip_atomic_load(p, __ATOMIC_RELAXED, __HIP_MEMORY_SCOPE_AGENT) < need) {
        __builtin_amdgcn_s_sleep(16);
        if ((++k & 63) == 0)
            (void)__hip_atomic_load(p, __ATOMIC_ACQUIRE, __HIP_MEMORY_SCOPE_AGENT);
    }
    (void)__hip_atomic_load(p, __ATOMIC_ACQUIRE, __HIP_MEMORY_SCOPE_AGENT);
}

// One LSTM layer scan for 16 batch rows. 3 register weight arrays — exactly 3
// fit the 256-reg/wave budget (512KB CU file / 8 waves); a 4th array or any
// higher occupancy forces global remat (r6/r10/r13: FETCH 7-17GB). No Wk_lo
// (r10: absmax 0.0112 < 0.0188). Double-buffered A -> ONE __syncthreads/step.
// PROD stores h0 as relaxed agent atomics (write-through; no wbl2) and
// publishes progress relaxed after the barrier. CONS (layer 1) accumulates
// 0.5*h1 straight into d_out via atomicAdd (merge kernel eliminated; exactly
// two commutative addends per element -> deterministic).
template<bool PROD>
__device__ __forceinline__ void run_layer(
    const float* __restrict__ Wk, const float* __restrict__ Wr,
    const float* __restrict__ Bv,
    const float* __restrict__ src,     // PROD: x; CONS: h0 buffer
    float* __restrict__ dst,           // PROD: h0 buffer; CONS: d_out
    u16* A, int* prog_c,
    const int dir, const int base_b,
    const int tid, const int q, const int cl, const int uu,
    const int sr, const int sc)
{
    // ---- resident weight fragments (B-side)
    bf16x8 wkh[4][4], wrh[4][4], wrl[4][4];
    #pragma unroll
    for (int g = 0; g < 4; ++g) {
        const int col = g * NU + uu;
        #pragma unroll
        for (int s = 0; s < 4; ++s) {
            bf16x8 fa, fh, fl;
            #pragma unroll
            for (int j = 0; j < 8; ++j) {
                const int k = s * 32 + q * 8 + j;
                fa[j] = (short)f2bf(Wk[k * NG + col]);
                const float w = Wr[k * NG + col];
                const u16 hi = f2bf(w);
                fh[j] = (short)hi;
                fl[j] = (short)f2bf(w - bf2f(hi));
            }
            wkh[g][s] = fa; wrh[g][s] = fh; wrl[g][s] = fl;
        }
    }
    float bias[4];
    #pragma unroll
    for (int g = 0; g < 4; ++g) bias[g] = Bv[g * NU + uu];

    // hoisted swizzled frag base offsets (u16 index), statically indexed
    uint32_t rb[4];
    #pragma unroll
    for (int s = 0; s < 4; ++s)
        rb[s] = (uint32_t)(cl * 1024 + ((s * 64 + q * 16) ^ ((cl & 15) << 4))) >> 1;

    for (int i = tid; i < LDS_A_ELEMS; i += 512) A[i] = 0;   // h planes start 0
    f32x4 cc = {0.f, 0.f, 0.f, 0.f};

    const size_t srow = (size_t)(base_b + sr) * (NT * NU) + sc;
    const uint32_t stg = (uint32_t)(sr * 1024 + ((2 * sc) ^ ((sr & 15) << 4))) >> 1;

    // consumer pre-gate: chunk 0 prefetches through x_{t(9)} -> need 10
    if (!PROD && tid == 0) spin_gate(prog_c, (CHUNK + 2 < NT) ? CHUNK + 2 : NT);
    __syncthreads();   // zeroing ordered before staging (r4 lesson) + gate broadcast

    // prologue: stage x0 into buffer 0; prefetch x1
    {
        const float4 v = *(const float4*)&src[srow + (size_t)(dir ? NT - 1 : 0) * NU];
        const float vv[4] = {v.x, v.y, v.z, v.w};
        u16x4 hi4, lo4;
        #pragma unroll
        for (int e = 0; e < 4; ++e) {
            const u16 h = f2bf(vv[e]);
            hi4[e] = h;
            lo4[e] = f2bf(vv[e] - bf2f(h));
        }
        *(u16x4*)&A[stg]       = hi4;
        *(u16x4*)&A[stg + 128] = lo4;
    }
    float4 cur = *(const float4*)&src[srow + (size_t)(dir ? NT - 2 : 1) * NU];
    __syncthreads();   // x0 staged, visible

    int p = 0;
    for (int cs = 0; cs < NT; cs += CHUNK) {
        // gate chunk cs: prefetches through x_{t(cs+9)} -> need cs+10
        if (!PROD && cs > 0) {
            if (tid == 0) {
                const int need = (cs + CHUNK + 2 < NT) ? cs + CHUNK + 2 : NT;
                spin_gate(prog_c, need);
            }
            __syncthreads();
        }

        for (int step = cs; step < cs + CHUNK; ++step) {
            const int t = dir ? (NT - 1 - step) : step;
            const u16* Ard = A + p * ABUF;
            u16*       Awr = A + (p ^ 1) * ABUF;

            // ---- stage x_{t+1} (prefetched last step) into the NEXT buffer
            if (step + 1 < NT) {
                const float vv[4] = {cur.x, cur.y, cur.z, cur.w};
                u16x4 hi4, lo4;
                #pragma unroll
                for (int e = 0; e < 4; ++e) {
                    const u16 h = f2bf(vv[e]);
                    hi4[e] = h;
                    lo4[e] = f2bf(vv[e] - bf2f(h));
                }
                *(u16x4*)&Awr[stg]       = hi4;   // x_hi: k in [0,128)
                *(u16x4*)&Awr[stg + 128] = lo4;   // x_lo: k in [128,256)
            }
            // ---- prefetch x_{t+2} for next step's staging
            if (step + 2 < NT) {
                const int tf = dir ? (NT - 3 - step) : (step + 2);
                cur = *(const float4*)&src[srow + (size_t)tf * NU];
            }

            f32x4 accx[4], acch[4];   // x-side (carries bias) and h-side chains
            #pragma unroll
            for (int g = 0; g < 4; ++g) {
                accx[g] = (f32x4){bias[g], bias[g], bias[g], bias[g]};
                acch[g] = (f32x4){0.f, 0.f, 0.f, 0.f};
            }

            #pragma unroll
            for (int s = 0; s < 4; ++s) {
                const bf16x8 axh = *(const bf16x8*)&Ard[rb[s]];
                const bf16x8 axl = *(const bf16x8*)&Ard[rb[s] + 128];
                const bf16x8 ahh = *(const bf16x8*)&Ard[rb[s] + 256];
                const bf16x8 ahl = *(const bf16x8*)&Ard[rb[s] + 384];
                #pragma unroll
                for (int g = 0; g < 4; ++g) {
                    accx[g] = __builtin_amdgcn_mfma_f32_16x16x32_bf16(axh, wkh[g][s], accx[g], 0, 0, 0);
                    accx[g] = __builtin_amdgcn_mfma_f32_16x16x32_bf16(axl, wkh[g][s], accx[g], 0, 0, 0);
                    acch[g] = __builtin_amdgcn_mfma_f32_16x16x32_bf16(ahh, wrh[g][s], acch[g], 0, 0, 0);
                    acch[g] = __builtin_amdgcn_mfma_f32_16x16x32_bf16(ahl, wrh[g][s], acch[g], 0, 0, 0);
                    acch[g] = __builtin_amdgcn_mfma_f32_16x16x32_bf16(ahh, wrl[g][s], acch[g], 0, 0, 0);
                }
            }

            // gates + state; C/D: col = lane&15 (unit), row = q*4+j (batch row)
            #pragma unroll
            for (int j = 0; j < 4; ++j) {
                const int r = q * 4 + j;
                const float gi = sigm(accx[0][j] + acch[0][j]);
                const float gf = sigm(accx[1][j] + acch[1][j]);
                const float gg = tanh_fast(accx[2][j] + acch[2][j]);
                const float go = sigm(accx[3][j] + acch[3][j]);
                const float cn = gf * cc[j] + gi * gg;
                cc[j] = cn;
                const float h = go * tanh_fast(cn);
                const u16 hh = f2bf(h);
                const u16 hl = f2bf(h - bf2f(hh));
                const uint32_t hb = (uint32_t)(r * 1024 + ((2 * uu) ^ ((r & 15) << 4)));
                Awr[(hb >> 1) + 256] = hh;   // h_hi plane of the NEXT buffer
                Awr[(hb >> 1) + 384] = hl;   // h_lo plane
                const size_t oidx =
                    (size_t)(base_b + r) * (NT * NU) + (size_t)t * NU + uu;
                if (PROD) {
                    // coherent store: at the coherence point once retired
                    __hip_atomic_store(&dst[oidx], h, __ATOMIC_RELAXED,
                                       __HIP_MEMORY_SCOPE_AGENT);
                } else {
                    atomicAdd(&dst[oidx], 0.5f * h);   // fused merge into d_out
                }
            }

            __syncthreads();   // the ONLY per-step barrier: p-reads done,
                               // p^1 writes visible, every wave's older
                               // stores drained (per-wave vmcnt at barrier)
            // publish step+1: h0[0..step] stored AND drained. No waitcnt —
            // the barrier is the proof (r14 lesson: an extra vmcnt(0) here
            // stalls tid0 on its own fresh prefetch).
            if (PROD && tid == 0)
                __hip_atomic_store(prog_c, step + 1, __ATOMIC_RELAXED,
                                   __HIP_MEMORY_SCOPE_AGENT);
            p ^= 1;
        }
    }
}

// grid = (64 groups, 2 dirs, 2 layers) = 256 blocks = 1 per CU, all
// co-resident -> consumer spins cannot deadlock (producers never wait).
// Producer (g,d,0) and consumer (g,d,1) share blockIdx.x%8 -> same XCD:
// the relaxed progress poll sees the producer's L2-local update directly.
__global__ __launch_bounds__(512, 2)
void lstm_scan(const float* __restrict__ x,
               const float* __restrict__ fwk, const float* __restrict__ fwrk,
               const float* __restrict__ fwb,
               const float* __restrict__ bwk, const float* __restrict__ bwrk,
               const float* __restrict__ bwb,
               float* __restrict__ buf_fw, float* __restrict__ buf_bw,
               float* __restrict__ dout, int* __restrict__ prog) {
    __shared__ __align__(16) u16 A[LDS_A_ELEMS];   // 2 x [16][512] bf16, swizzled

    const int tid   = threadIdx.x;
    const int lane  = tid & 63;
    const int wv    = tid >> 6;         // wave 0..7
    const int grp   = blockIdx.x;       // 0..63
    const int dir   = blockIdx.y;       // 0 = fw, 1 = bw
    const int layer = blockIdx.z;       // 0 = producer, 1 = consumer
    const int base_b = grp * ROWS;

    const float* kp = dir ? bwk  : fwk;
    const float* rp = dir ? bwrk : fwrk;
    const float* bp = dir ? bwb  : fwb;
    float* buf = dir ? buf_bw : buf_fw;
    int* prog_c = prog + dir * NGRP + grp;

    const int q  = lane >> 4;           // k-group 0..3
    const int cl = lane & 15;           // A-row / B-col within tile
    const int uu = (wv << 4) + cl;      // unit 0..127 owned by this lane

    const int sr = tid >> 5;            // staging row 0..15
    const int sc = (tid & 31) << 2;     // staging col 0..124

    if (layer == 0) {
        // layer 0: x -> buf (h0), publishing progress per step
        run_layer<true>(kp, rp, bp, x, buf, A, prog_c,
                        dir, base_b, tid, q, cl, uu, sr, sc);
    } else {
        // layer 1: buf (h0) -> 0.5*h1 accumulated into d_out, gated on
        // producer progress. buf is read-only here (no aliasing).
        run_layer<false>(kp + ND * NG, rp + NU * NG, bp + NG,
                         buf, dout, A, prog_c,
                         dir, base_b, tid, q, cl, uu, sr, sc);
    }
}

extern "C" void kernel_launch(void* const* d_in, const int* in_sizes, int n_in,
                              void* d_out, int out_size, void* d_ws, size_t ws_size,
                              hipStream_t stream) {
    const float* x    = (const float*)d_in[0];
    const float* fwk  = (const float*)d_in[1];
    const float* fwrk = (const float*)d_in[2];
    const float* fwb  = (const float*)d_in[3];
    const float* bwk  = (const float*)d_in[4];
    const float* bwrk = (const float*)d_in[5];
    const float* bwb  = (const float*)d_in[6];
    float* out = (float*)d_out;

    const size_t seq = (size_t)NB * NT * NU;     // 26,214,400 elements
    float* buf_fw = (float*)d_ws;                // fw h0 sequence
    float* buf_bw = buf_fw + seq;                // bw h0 sequence
    int*   prog   = (int*)(buf_bw + seq);        // per-chain progress counters

    // deterministic replay: zero counters and the atomicAdd target each launch
    hipMemsetAsync(prog, 0, 2 * NGRP * sizeof(int), stream);
    hipMemsetAsync(out, 0, (size_t)out_size * sizeof(float), stream);

    lstm_scan<<<dim3(NGRP, 2, 2), 512, 0, stream>>>(
        x, fwk, fwrk, fwb, bwk, bwrk, bwb, buf_fw, buf_bw, out, prog);
}